// Round 1
// baseline (453.914 us; speedup 1.0000x reference)
//
#include <hip/hip_runtime.h>
#include <hip/hip_bf16.h>

#define S_LEN 50
#define BATCH 128
#define DIM 256
#define NITEMS 50001
#define NPAD 50048
#define GDIM 768
#define NSEQ 6400  // S_LEN*BATCH

typedef __attribute__((ext_vector_type(8))) short short8;
typedef __attribute__((ext_vector_type(4))) short short4_;
typedef __attribute__((ext_vector_type(4))) float float4_;

static __device__ __forceinline__ unsigned short f2bf(float x){
  union { float f; unsigned u; } v; v.f = x;
  unsigned r = v.u + 0x7FFFu + ((v.u >> 16) & 1u);
  return (unsigned short)(r >> 16);
}
static __device__ __forceinline__ float bf2f(unsigned short h){
  union { unsigned u; float f; } v; v.u = ((unsigned)h) << 16;
  return v.f;
}
static __device__ __forceinline__ float sigm(float x){ return 1.f/(1.f + __expf(-x)); }

// ---------------- kernel 1: convert W_ih / W_hh to bf16 ----------------
__global__ void k_conv_w(const float* __restrict__ a, const float* __restrict__ b,
                         unsigned short* __restrict__ oa, unsigned short* __restrict__ ob, int n4){
  int i = blockIdx.x*256 + threadIdx.x;
  if (i >= n4) return;
  float4_ x = ((const float4_*)a)[i];
  float4_ y = ((const float4_*)b)[i];
  short4_ u, v;
  #pragma unroll
  for (int j=0;j<4;j++){ u[j] = (short)f2bf(x[j]); v[j] = (short)f2bf(y[j]); }
  ((short4_*)oa)[i] = u;
  ((short4_*)ob)[i] = v;
}

// ---------------- kernel 2: emb -> bf16 + tcw = softmax(emb @ embp.T) ----------------
__global__ void k_emb(const float* __restrict__ emb, const float* __restrict__ embp,
                      unsigned short* __restrict__ emb_bf, float* __restrict__ tcw){
  int wid = (blockIdx.x*256 + threadIdx.x) >> 6;
  int lane = threadIdx.x & 63;
  if (wid >= NITEMS) return;
  float4_ v = ((const float4_*)(emb + (size_t)wid*DIM))[lane];
  short4_ o;
  #pragma unroll
  for (int j=0;j<4;j++) o[j] = (short)f2bf(v[j]);
  ((short4_*)emb_bf)[(size_t)wid*64 + lane] = o;
  const float4_* pp = (const float4_*)embp;
  float4_ e0 = pp[lane], e1 = pp[64+lane], e2 = pp[128+lane];
  float d0=0.f,d1=0.f,d2=0.f;
  #pragma unroll
  for (int j=0;j<4;j++){ d0 += v[j]*e0[j]; d1 += v[j]*e1[j]; d2 += v[j]*e2[j]; }
  #pragma unroll
  for (int off=32; off; off>>=1){ d0 += __shfl_xor(d0,off); d1 += __shfl_xor(d1,off); d2 += __shfl_xor(d2,off); }
  if (lane == 0){
    float m = fmaxf(d0, fmaxf(d1,d2));
    float a0 = __expf(d0-m), a1 = __expf(d1-m), a2 = __expf(d2-m);
    float inv = 1.f/(a0+a1+a2);
    tcw[wid*3+0] = a0*inv; tcw[wid*3+1] = a1*inv; tcw[wid*3+2] = a2*inv;
  }
}

// ---------------- kernel 3: gather x (bf16) + concen softmax -> cf ----------------
__global__ void k_gather(const int* __restrict__ seq, const float* __restrict__ emb,
                         const float* __restrict__ embp, unsigned short* __restrict__ x_bf,
                         float* __restrict__ cfb){
  int wid = (blockIdx.x*256 + threadIdx.x) >> 6;   // wid = s*128 + b
  int lane = threadIdx.x & 63;
  if (wid >= NSEQ) return;
  int s = wid >> 7, b = wid & 127;
  int item = seq[s*BATCH + b];
  float4_ v = ((const float4_*)(emb + (size_t)item*DIM))[lane];
  short4_ o;
  #pragma unroll
  for (int j=0;j<4;j++) o[j] = (short)f2bf(v[j]);
  ((short4_*)x_bf)[(size_t)wid*64 + lane] = o;
  const float4_* pp = (const float4_*)embp;
  float4_ e0 = pp[lane], e1 = pp[64+lane], e2 = pp[128+lane];
  float d0=0.f,d1=0.f,d2=0.f;
  #pragma unroll
  for (int j=0;j<4;j++){ d0 += v[j]*e0[j]; d1 += v[j]*e1[j]; d2 += v[j]*e2[j]; }
  #pragma unroll
  for (int off=32; off; off>>=1){ d0 += __shfl_xor(d0,off); d1 += __shfl_xor(d1,off); d2 += __shfl_xor(d2,off); }
  if (lane == 0){
    float m = fmaxf(d0, fmaxf(d1,d2));
    float a0 = __expf((d0-m)*10.f), a1 = __expf((d1-m)*10.f), a2 = __expf((d2-m)*10.f);
    float inv = (item != 0) ? 1.f/(a0+a1+a2) : 0.f;   // mask fused in
    float c0 = a0*inv, c1 = a1*inv, c2 = a2*inv;
    cfb[wid]          = (c0 >= 0.01f) ? c0 : 0.f;
    cfb[NSEQ + wid]   = (c1 >= 0.01f) ? c1 : 0.f;
    cfb[2*NSEQ + wid] = (c2 >= 0.01f) ? c2 : 0.f;
  }
}

// ---------------- kernel 4: gi = x @ W_ih.T + b_ih  (bf16 out) ----------------
__global__ __launch_bounds__(256) void k_gi(const unsigned short* __restrict__ x_bf,
        const unsigned short* __restrict__ wih_bf, const float* __restrict__ bih,
        unsigned short* __restrict__ gi_bf){
  int p  = blockIdx.z;
  int n0 = blockIdx.x * 64;
  int m0 = blockIdx.y * 64 + (threadIdx.x >> 6) * 16;
  int lane = threadIdx.x & 63;
  int col = lane & 15, q = lane >> 4, kq = q*8;
  const unsigned short* W = wih_bf + (size_t)p*GDIM*DIM;
  const unsigned short* A = x_bf + (size_t)(m0 + col)*DIM + kq;
  float4_ z4 = {0.f,0.f,0.f,0.f};
  float4_ acc[4];
  #pragma unroll
  for (int t=0;t<4;t++) acc[t] = z4;
  #pragma unroll
  for (int kf=0; kf<8; kf++){
    short8 a = *(const short8*)(A + kf*32);
    #pragma unroll
    for (int t=0;t<4;t++){
      short8 bb = *(const short8*)(W + (size_t)(n0 + t*16 + col)*DIM + kf*32 + kq);
      acc[t] = __builtin_amdgcn_mfma_f32_16x16x32_bf16(a, bb, acc[t], 0, 0, 0);
    }
  }
  #pragma unroll
  for (int t=0;t<4;t++){
    int n = n0 + t*16 + col;
    float bv = bih[p*GDIM + n];
    #pragma unroll
    for (int i=0;i<4;i++){
      int m = m0 + 4*q + i;
      gi_bf[((size_t)p*NSEQ + m)*GDIM + n] = f2bf(acc[t][i] + bv);
    }
  }
}

// ---------------- kernel 5: 50-step PSRU recurrence ----------------
// grid = 24 blocks: (p, 16-batch-slice). 512 thr = 8 waves; wave w owns gate
// cols [c*256 + w*32, +32) for c=r,z,n -> computes h dims [w*32, w*32+32).
// h state f32 in LDS; bf16 copy (XOR-swizzled rows) feeds MFMA A-frags.
// W_hh streamed from L2 each step (L2-resident: 393KB bf16/purpose).
__global__ __launch_bounds__(512, 1) void k_rnn(const unsigned short* __restrict__ whh_bf,
         const unsigned short* __restrict__ gi_bf, const float* __restrict__ bhh,
         const float* __restrict__ cfb, unsigned short* __restrict__ hn_bf){
  extern __shared__ char lds[];
  // lds layout: [0,16384): h_bf16[2][16][256] (512B rows, byte^((row&7)<<4) swizzle)
  //             [16384,49152): h_f32[2][16][256] ; [49152,52352): cf[50][16]
  float* hf  = (float*)(lds + 16384);
  float* cfs = (float*)(lds + 49152);
  int p  = blockIdx.x >> 3;
  int b0 = (blockIdx.x & 7) * 16;
  int tid = threadIdx.x;
  int w = tid >> 6, lane = tid & 63;
  for (int i = tid; i < 8192; i += 512){ ((unsigned short*)lds)[i] = 0; hf[i] = 0.f; }
  for (int i = tid; i < 800; i += 512) cfs[i] = cfb[p*NSEQ + (i>>4)*BATCH + b0 + (i&15)];
  __syncthreads();
  int col = lane & 15;
  int q = lane >> 4;
  int kq = q * 8;
  int swz = (lane & 7) << 4;
  const unsigned short* Wp = whh_bf + (size_t)p*GDIM*DIM;
  int gcol[6]; float bias[6];
  #pragma unroll
  for (int t=0;t<6;t++){
    gcol[t] = (t>>1)*256 + w*32 + (t&1)*16 + col;   // t: 0,1=r  2,3=z  4,5=n
    bias[t] = bhh[p*GDIM + gcol[t]];
  }
  float4_ z4 = {0.f,0.f,0.f,0.f};
  for (int s = 0; s < S_LEN; s++){
    int rbuf = s & 1, wbuf = rbuf ^ 1;
    const unsigned short* gp = gi_bf + ((size_t)p*NSEQ + s*BATCH + b0)*GDIM;
    float giv[6][4];
    #pragma unroll
    for (int t=0;t<6;t++){
      #pragma unroll
      for (int i=0;i<4;i++)
        giv[t][i] = bf2f(gp[(size_t)(4*q+i)*GDIM + gcol[t]]);
    }
    float4_ acc[6];
    #pragma unroll
    for (int t=0;t<6;t++) acc[t] = z4;
    const char* hrow = lds + rbuf*8192 + col*512;
    #pragma unroll
    for (int kf=0; kf<8; kf++){
      short8 a = *(const short8*)(hrow + ((kf*64 + q*16) ^ swz));
      #pragma unroll
      for (int t=0;t<6;t++){
        short8 bb = *(const short8*)(Wp + ((size_t)gcol[t] << 8) + kf*32 + kq);
        acc[t] = __builtin_amdgcn_mfma_f32_16x16x32_bf16(a, bb, acc[t], 0, 0, 0);
      }
    }
    #pragma unroll
    for (int t=0;t<2;t++){
      #pragma unroll
      for (int i=0;i<4;i++){
        int rb = 4*q + i;
        int d = w*32 + t*16 + col;
        float r = sigm(giv[t][i]   + acc[t][i]   + bias[t]);
        float z = sigm(giv[t+2][i] + acc[t+2][i] + bias[t+2]);
        float pre = giv[t+4][i] + r*(acc[t+4][i] + bias[t+4]);
        float n = 1.f - 2.f/(__expf(2.f*pre) + 1.f);        // tanh, NaN-safe
        float cfv = cfs[s*16 + rb];
        float ho = hf[rbuf*4096 + rb*256 + d];
        float hy = ho - cfv*z*(ho - n);
        hf[wbuf*4096 + rb*256 + d] = hy;
        *(unsigned short*)(lds + wbuf*8192 + rb*512 + ((2*d) ^ ((rb&7)<<4))) = f2bf(hy);
      }
    }
    __syncthreads();
  }
  // final state lives in buf 0 (50 steps -> last write to wbuf=0)
  for (int i = tid; i < 16*DIM; i += 512)
    hn_bf[((size_t)p*BATCH + b0 + (i>>8))*DIM + (i & 255)] = f2bf(hf[i]);
}

// ---------------- kernel 6: scores = sum_p tcw[t,p] * (hn_p @ emb.T) ----------------
__global__ __launch_bounds__(256) void k_score(const unsigned short* __restrict__ emb_bf,
        const unsigned short* __restrict__ hn_bf, const float* __restrict__ tcw,
        float* __restrict__ out){
  int w = threadIdx.x >> 6, lane = threadIdx.x & 63;
  int col = lane & 15, q = lane >> 4, kq = q*8;
  int trow = blockIdx.x*64 + w*16 + col;
  float4_ z4 = {0.f,0.f,0.f,0.f};
  float4_ acc[3][8];
  #pragma unroll
  for (int p=0;p<3;p++){
    #pragma unroll
    for (int m=0;m<8;m++) acc[p][m] = z4;
  }
  const unsigned short* E = emb_bf + (size_t)trow*DIM + kq;
  #pragma unroll
  for (int kf=0; kf<8; kf++){
    short8 bb = *(const short8*)(E + kf*32);
    #pragma unroll
    for (int p=0;p<3;p++){
      #pragma unroll
      for (int m=0;m<8;m++){
        short8 a = *(const short8*)(hn_bf + ((size_t)p*BATCH + m*16 + col)*DIM + kf*32 + kq);
        acc[p][m] = __builtin_amdgcn_mfma_f32_16x16x32_bf16(a, bb, acc[p][m], 0, 0, 0);
      }
    }
  }
  if (trow < NITEMS){
    float w0 = tcw[trow*3+0], w1 = tcw[trow*3+1], w2 = tcw[trow*3+2];
    #pragma unroll
    for (int m=0;m<8;m++){
      #pragma unroll
      for (int i=0;i<4;i++){
        int b = m*16 + 4*q + i;
        out[(size_t)b*NITEMS + trow] = w0*acc[0][m][i] + w1*acc[1][m][i] + w2*acc[2][m][i];
      }
    }
  }
}

extern "C" void kernel_launch(void* const* d_in, const int* in_sizes, int n_in,
                              void* d_out, int out_size, void* d_ws, size_t ws_size,
                              hipStream_t stream) {
  const int*   seq  = (const int*)d_in[0];
  const float* emb  = (const float*)d_in[1];
  const float* embp = (const float*)d_in[2];
  const float* wih  = (const float*)d_in[3];
  const float* whh  = (const float*)d_in[4];
  const float* bih  = (const float*)d_in[5];
  const float* bhh  = (const float*)d_in[6];
  float* out = (float*)d_out;

  char* ws = (char*)d_ws;
  size_t off = 0;
  auto alloc = [&](size_t bytes) -> void* {
    void* r = ws + off; off += (bytes + 255) & ~(size_t)255; return r;
  };
  unsigned short* emb_bf = (unsigned short*)alloc((size_t)NPAD*DIM*2);
  unsigned short* x_bf   = (unsigned short*)alloc((size_t)NSEQ*DIM*2);
  unsigned short* wih_bf = (unsigned short*)alloc((size_t)3*GDIM*DIM*2);
  unsigned short* whh_bf = (unsigned short*)alloc((size_t)3*GDIM*DIM*2);
  unsigned short* gi_bf  = (unsigned short*)alloc((size_t)3*NSEQ*GDIM*2);
  float* tcw = (float*)alloc((size_t)NITEMS*3*4);
  float* cfb = (float*)alloc((size_t)3*NSEQ*4);
  unsigned short* hn_bf = (unsigned short*)alloc((size_t)3*BATCH*DIM*2);

  k_conv_w<<<1152, 256, 0, stream>>>(wih, whh, wih_bf, whh_bf, 3*GDIM*DIM/4);
  k_emb<<<(NITEMS+3)/4, 256, 0, stream>>>(emb, embp, emb_bf, tcw);
  k_gather<<<NSEQ/4, 256, 0, stream>>>(seq, emb, embp, x_bf, cfb);
  dim3 gg(GDIM/64, NSEQ/64, 3);
  k_gi<<<gg, 256, 0, stream>>>(x_bf, wih_bf, bih, gi_bf);

  hipError_t e = hipFuncSetAttribute((const void*)k_rnn,
                    hipFuncAttributeMaxDynamicSharedMemorySize, 98304);
  size_t shmem = (e == hipSuccess) ? 98304 : 53248;  // 98KB pads LDS to force 1 block/CU
  k_rnn<<<24, 512, shmem, stream>>>(whh_bf, gi_bf, bhh, cfb, hn_bf);

  k_score<<<NPAD/64, 256, 0, stream>>>(emb_bf, hn_bf, tcw, out);
}